// Round 11
// baseline (26.517 us; speedup 1.0000x reference)
//
#include <hip/hip_runtime.h>
#include <math.h>

#define BB   16
#define VV   8
#define HW_  65536            // 256*256
#define NBLK 4096             // single-wave blocks: fine-grained balance of vc-variable work
#define NTHR 64
#define NPIX_D 3145728.0      // B*3*H*W (mean denominator)

// access j-th float of a float4 (static j under full unroll)
#define F4(a, j) (((const float*)&(a))[j])

__global__ __launch_bounds__(NTHR) void pvs_main(
    const float* __restrict__ y0,
    const float* __restrict__ ycond,
    const float* __restrict__ angle,
    const float* __restrict__ noise,
    const float* __restrict__ rand_u,
    const float* __restrict__ Wk,
    const float* __restrict__ bk,
    const float* __restrict__ gammas,
    const int*   __restrict__ view_count,
    const int*   __restrict__ tt,
    float* __restrict__ partials)
{
    const int tid = threadIdx.x;
    // batch-interleaved mapping: b block-uniform, consecutive blocks cover
    // all 16 batches (vc load balance across CUs/XCDs)
    const int b   = blockIdx.x & (BB - 1);
    const int pos = blockIdx.x >> 4;             // 0..255 chunk within plane
    const int hw  = (pos << 8) | (tid << 2);     // 4-pixel base in plane

    // per-batch scalars — block-uniform -> scalar ops
    const int   t  = tt[b];
    const float g1 = gammas[t - 1];
    const float g2 = gammas[t];
    const float sg = (g2 - g1) * rand_u[b] + g1;
    const float sq  = sqrtf(sg);
    const float sq1 = sqrtf(1.0f - sg);
    const float md  = 0.1f * (sg + angle[b]);
    // force SGPR so view guards are scalar branches (loads never issued
    // for masked views; no divergence since b is block-uniform)
    const int vcs = __builtin_amdgcn_readfirstlane(view_count[b]);

    // Wk (4,6) row-major, bk (4) — uniform, L1-resident
    float wk[4][6], bkr[4];
    #pragma unroll
    for (int o = 0; o < 4; ++o) {
        bkr[o] = bk[o];
        #pragma unroll
        for (int c = 0; c < 6; ++c) wk[o][c] = Wk[o * 6 + c];
    }

    // ---- loads up front (r10-proven ordering): y0, noise, then guarded ycond ----
    float4 y0v[3], nzv[3];
    #pragma unroll
    for (int c = 0; c < 3; ++c) {
        y0v[c] = *(const float4*)(y0    + (b * 3 + c) * HW_ + hw);
        nzv[c] = *(const float4*)(noise + (b * 3 + c) * HW_ + hw);
    }
    float4 ycv[VV][3];
    #pragma unroll
    for (int v = 0; v < VV; ++v) {
        if (v < vcs) {
            #pragma unroll
            for (int c = 0; c < 3; ++c) {
                ycv[v][c] = *(const float4*)(ycond + ((b * VV + v) * 3 + c) * HW_ + hw);
            }
        } else {
            #pragma unroll
            for (int c = 0; c < 3; ++c) {
                ycv[v][c] = make_float4(0.f, 0.f, 0.f, 0.f);
            }
        }
    }

    float acc = 0.0f;
    #pragma unroll
    for (int j = 0; j < 4; ++j) {
        // y_noisy for this pixel
        float yn0 = fmaf(sq, F4(y0v[0], j), sq1 * F4(nzv[0], j));
        float yn1 = fmaf(sq, F4(y0v[1], j), sq1 * F4(nzv[1], j));
        float yn2 = fmaf(sq, F4(y0v[2], j), sq1 * F4(nzv[2], j));

        // v-independent part of the 4x6 linear layer
        float base[4];
        #pragma unroll
        for (int o = 0; o < 4; ++o) {
            base[o] = fmaf(wk[o][3], yn0,
                      fmaf(wk[o][4], yn1,
                      fmaf(wk[o][5], yn2, bkr[o] + md)));
        }

        // single-pass masked softmax over views, LINEARIZED:
        //   noise_hat_o * S = A_o . (sum_v w_v x_v) + base_o * S
        // masked views skipped entirely under scalar branch.
        // (no max-shift: |logit| <= ~1.5, absmax 0.0 validated r2-r10)
        float S = 0.0f, sx0 = 0.0f, sx1 = 0.0f, sx2 = 0.0f;
        #pragma unroll
        for (int v = 0; v < VV; ++v) {
            if (v < vcs) {
                float x0 = F4(ycv[v][0], j);
                float x1 = F4(ycv[v][1], j);
                float x2 = F4(ycv[v][2], j);
                float o3 = fmaf(wk[3][0], x0,
                           fmaf(wk[3][1], x1,
                           fmaf(wk[3][2], x2, base[3])));
                float w  = __expf(o3);
                S   += w;
                sx0  = fmaf(w, x0, sx0);
                sx1  = fmaf(w, x1, sx1);
                sx2  = fmaf(w, x2, sx2);
            }
        }
        float nh0 = fmaf(wk[0][0], sx0,
                    fmaf(wk[0][1], sx1,
                    fmaf(wk[0][2], sx2, base[0] * S)));
        float nh1 = fmaf(wk[1][0], sx0,
                    fmaf(wk[1][1], sx1,
                    fmaf(wk[1][2], sx2, base[1] * S)));
        float nh2 = fmaf(wk[2][0], sx0,
                    fmaf(wk[2][1], sx1,
                    fmaf(wk[2][2], sx2, base[2] * S)));
        float invS = 1.0f / S;
        float d0 = F4(nzv[0], j) - nh0 * invS;
        float d1 = F4(nzv[1], j) - nh1 * invS;
        float d2 = F4(nzv[2], j) - nh2 * invS;
        acc = fmaf(d0, d0, fmaf(d1, d1, fmaf(d2, d2, acc)));
    }

    // deterministic wave reduction (single-wave block: no LDS, no barrier)
    #pragma unroll
    for (int s = 32; s > 0; s >>= 1) acc += __shfl_down(acc, s, 64);
    if (tid == 0) partials[blockIdx.x] = acc;
}

__global__ __launch_bounds__(256) void pvs_reduce(const float* __restrict__ partials,
                                                 float* __restrict__ out)
{
    __shared__ double s[256];
    double a = 0.0;
    for (int i = threadIdx.x; i < NBLK; i += 256) a += (double)partials[i];
    s[threadIdx.x] = a;
    __syncthreads();
    #pragma unroll
    for (int st = 128; st > 0; st >>= 1) {
        if (threadIdx.x < st) s[threadIdx.x] += s[threadIdx.x + st];
        __syncthreads();
    }
    if (threadIdx.x == 0) out[0] = (float)(s[0] / NPIX_D);
}

extern "C" void kernel_launch(void* const* d_in, const int* in_sizes, int n_in,
                              void* d_out, int out_size, void* d_ws, size_t ws_size,
                              hipStream_t stream) {
    const float* y0      = (const float*)d_in[0];
    const float* ycond   = (const float*)d_in[1];
    const float* angle   = (const float*)d_in[2];
    const float* noise   = (const float*)d_in[3];
    const float* rand_u  = (const float*)d_in[4];
    const float* Wk      = (const float*)d_in[5];
    const float* bk      = (const float*)d_in[6];
    const float* gammas  = (const float*)d_in[7];
    const int*   vcp     = (const int*)d_in[8];
    const int*   tt      = (const int*)d_in[9];

    float* partials = (float*)d_ws;
    float* out      = (float*)d_out;

    pvs_main<<<NBLK, NTHR, 0, stream>>>(y0, ycond, angle, noise, rand_u,
                                        Wk, bk, gammas, vcp, tt, partials);
    pvs_reduce<<<1, 256, 0, stream>>>(partials, out);
}

// Round 12
// 23.984 us; speedup vs baseline: 1.1056x; 1.1056x over previous
//
#include <hip/hip_runtime.h>
#include <math.h>

#define BB   16
#define VV   8
#define HW_  65536            // 256*256
#define HWQ  16384            // HW_/4
#define NQUAD (BB * HWQ)      // 262144 quads (4 pixels each)
#define NBLK 2048
#define NTHR 128
#define NRED 1024             // reduce-kernel threads
#define NPIX_D 3145728.0      // B*3*H*W (mean denominator)

// access j-th float of a float4 (static j under full unroll)
#define F4(a, j) (((const float*)&(a))[j])

__global__ __launch_bounds__(NTHR) void pvs_main(
    const float* __restrict__ y0,
    const float* __restrict__ ycond,
    const float* __restrict__ angle,
    const float* __restrict__ noise,
    const float* __restrict__ rand_u,
    const float* __restrict__ Wk,
    const float* __restrict__ bk,
    const float* __restrict__ gammas,
    const int*   __restrict__ view_count,
    const int*   __restrict__ tt,
    float* __restrict__ partials)
{
    __shared__ float s_sq[BB], s_sq1[BB], s_mod[BB];
    __shared__ int   s_vc[BB];
    __shared__ float s_red[NTHR];

    if (threadIdx.x < BB) {
        int b = threadIdx.x;
        int t = tt[b];
        float g1 = gammas[t - 1];
        float g2 = gammas[t];
        float sg = (g2 - g1) * rand_u[b] + g1;
        s_sq[b]  = sqrtf(sg);
        s_sq1[b] = sqrtf(1.0f - sg);
        s_mod[b] = 0.1f * (sg + angle[b]);
        s_vc[b]  = view_count[b];
    }
    __syncthreads();

    // Wk (4,6) row-major, bk (4) — uniform, L1-resident
    float wk[4][6], bkr[4];
    #pragma unroll
    for (int o = 0; o < 4; ++o) {
        bkr[o] = bk[o];
        #pragma unroll
        for (int c = 0; c < 6; ++c) wk[o][c] = Wk[o * 6 + c];
    }

    float acc = 0.0f;
    for (int q = blockIdx.x * NTHR + threadIdx.x; q < NQUAD; q += NBLK * NTHR) {
        // batch-interleaved mapping: b uniform per block (q>>8 constant over a
        // 128-thread block), batches spread across consecutive block pairs
        int blk = q >> 8;                               // 256-px chunk index
        int b   = blk & (BB - 1);                       // batch (block-uniform)
        int hw  = ((((blk >> 4) << 8) | (q & 255)) << 2);  // 4-pixel base in plane
        float sq = s_sq[b], sq1 = s_sq1[b], md = s_mod[b];
        // vc block-uniform -> SGPR: scalar branches, masked views' loads never issued
        const int vcs = __builtin_amdgcn_readfirstlane(s_vc[b]);

        float4 y0v[3], nzv[3];
        #pragma unroll
        for (int c = 0; c < 3; ++c) {
            y0v[c] = *(const float4*)(y0    + (b * 3 + c) * HW_ + hw);
            nzv[c] = *(const float4*)(noise + (b * 3 + c) * HW_ + hw);
        }
        // conditional ycond loads: only views v < vc are ever needed
        float4 ycv[VV][3];
        #pragma unroll
        for (int v = 0; v < VV; ++v) {
            if (v < vcs) {
                #pragma unroll
                for (int c = 0; c < 3; ++c) {
                    ycv[v][c] = *(const float4*)(ycond + ((b * VV + v) * 3 + c) * HW_ + hw);
                }
            } else {
                #pragma unroll
                for (int c = 0; c < 3; ++c) {
                    ycv[v][c] = make_float4(0.f, 0.f, 0.f, 0.f);
                }
            }
        }

        #pragma unroll
        for (int j = 0; j < 4; ++j) {
            // y_noisy for this pixel
            float yn0 = fmaf(sq, F4(y0v[0], j), sq1 * F4(nzv[0], j));
            float yn1 = fmaf(sq, F4(y0v[1], j), sq1 * F4(nzv[1], j));
            float yn2 = fmaf(sq, F4(y0v[2], j), sq1 * F4(nzv[2], j));

            // v-independent part of the 4x6 linear layer
            float base[4];
            #pragma unroll
            for (int o = 0; o < 4; ++o) {
                base[o] = fmaf(wk[o][3], yn0,
                          fmaf(wk[o][4], yn1,
                          fmaf(wk[o][5], yn2, bkr[o] + md)));
            }

            // single-pass masked softmax over views, LINEARIZED:
            //   noise_hat_o * S = A_o . (sum_v w_v x_v) + base_o * S
            // masked views skipped entirely under scalar branch.
            // (no max-shift: |logit| <= ~1.5, absmax 0.0 validated r2-r11)
            float S = 0.0f, sx0 = 0.0f, sx1 = 0.0f, sx2 = 0.0f;
            #pragma unroll
            for (int v = 0; v < VV; ++v) {
                if (v < vcs) {
                    float x0 = F4(ycv[v][0], j);
                    float x1 = F4(ycv[v][1], j);
                    float x2 = F4(ycv[v][2], j);
                    float o3 = fmaf(wk[3][0], x0,
                               fmaf(wk[3][1], x1,
                               fmaf(wk[3][2], x2, base[3])));
                    float w  = __expf(o3);
                    S   += w;
                    sx0  = fmaf(w, x0, sx0);
                    sx1  = fmaf(w, x1, sx1);
                    sx2  = fmaf(w, x2, sx2);
                }
            }
            float nh0 = fmaf(wk[0][0], sx0,
                        fmaf(wk[0][1], sx1,
                        fmaf(wk[0][2], sx2, base[0] * S)));
            float nh1 = fmaf(wk[1][0], sx0,
                        fmaf(wk[1][1], sx1,
                        fmaf(wk[1][2], sx2, base[1] * S)));
            float nh2 = fmaf(wk[2][0], sx0,
                        fmaf(wk[2][1], sx1,
                        fmaf(wk[2][2], sx2, base[2] * S)));
            float invS = 1.0f / S;
            float d0 = F4(nzv[0], j) - nh0 * invS;
            float d1 = F4(nzv[1], j) - nh1 * invS;
            float d2 = F4(nzv[2], j) - nh2 * invS;
            acc = fmaf(d0, d0, fmaf(d1, d1, fmaf(d2, d2, acc)));
        }
    }

    // deterministic block reduction
    s_red[threadIdx.x] = acc;
    __syncthreads();
    #pragma unroll
    for (int s = NTHR / 2; s > 0; s >>= 1) {
        if (threadIdx.x < s) s_red[threadIdx.x] += s_red[threadIdx.x + s];
        __syncthreads();
    }
    if (threadIdx.x == 0) partials[blockIdx.x] = s_red[0];
}

__global__ __launch_bounds__(NRED) void pvs_reduce(const float* __restrict__ partials,
                                                  float* __restrict__ out)
{
    __shared__ double s[NRED];
    double a = 0.0;
    for (int i = threadIdx.x; i < NBLK; i += NRED) a += (double)partials[i];
    s[threadIdx.x] = a;
    __syncthreads();
    #pragma unroll
    for (int st = NRED / 2; st > 0; st >>= 1) {
        if (threadIdx.x < st) s[threadIdx.x] += s[threadIdx.x + st];
        __syncthreads();
    }
    if (threadIdx.x == 0) out[0] = (float)(s[0] / NPIX_D);
}

extern "C" void kernel_launch(void* const* d_in, const int* in_sizes, int n_in,
                              void* d_out, int out_size, void* d_ws, size_t ws_size,
                              hipStream_t stream) {
    const float* y0      = (const float*)d_in[0];
    const float* ycond   = (const float*)d_in[1];
    const float* angle   = (const float*)d_in[2];
    const float* noise   = (const float*)d_in[3];
    const float* rand_u  = (const float*)d_in[4];
    const float* Wk      = (const float*)d_in[5];
    const float* bk      = (const float*)d_in[6];
    const float* gammas  = (const float*)d_in[7];
    const int*   vcp     = (const int*)d_in[8];
    const int*   tt      = (const int*)d_in[9];

    float* partials = (float*)d_ws;
    float* out      = (float*)d_out;

    pvs_main<<<NBLK, NTHR, 0, stream>>>(y0, ycond, angle, noise, rand_u,
                                        Wk, bk, gammas, vcp, tt, partials);
    pvs_reduce<<<1, NRED, 0, stream>>>(partials, out);
}

// Round 13
// 23.390 us; speedup vs baseline: 1.1337x; 1.0254x over previous
//
#include <hip/hip_runtime.h>
#include <math.h>

#define BB   16
#define VV   8
#define HW_  65536            // 256*256
#define HWQ  16384            // HW_/4
#define NQUAD (BB * HWQ)      // 262144 quads (4 pixels each)
#define NBLK 1024
#define NTHR 256
#define NPIX_D 3145728.0      // B*3*H*W (mean denominator)

// access j-th float of a float4 (static j under full unroll)
#define F4(a, j) (((const float*)&(a))[j])

__global__ __launch_bounds__(NTHR) void pvs_main(
    const float* __restrict__ y0,
    const float* __restrict__ ycond,
    const float* __restrict__ angle,
    const float* __restrict__ noise,
    const float* __restrict__ rand_u,
    const float* __restrict__ Wk,
    const float* __restrict__ bk,
    const float* __restrict__ gammas,
    const int*   __restrict__ view_count,
    const int*   __restrict__ tt,
    float* __restrict__ partials)
{
    __shared__ float s_sq[BB], s_sq1[BB], s_mod[BB];
    __shared__ int   s_vc[BB];
    __shared__ float s_red[NTHR];

    if (threadIdx.x < BB) {
        int b = threadIdx.x;
        int t = tt[b];
        float g1 = gammas[t - 1];
        float g2 = gammas[t];
        float sg = (g2 - g1) * rand_u[b] + g1;
        s_sq[b]  = sqrtf(sg);
        s_sq1[b] = sqrtf(1.0f - sg);
        s_mod[b] = 0.1f * (sg + angle[b]);
        s_vc[b]  = view_count[b];
    }
    __syncthreads();

    // Wk (4,6) row-major, bk (4) — uniform, L1-resident
    float wk[4][6], bkr[4];
    #pragma unroll
    for (int o = 0; o < 4; ++o) {
        bkr[o] = bk[o];
        #pragma unroll
        for (int c = 0; c < 6; ++c) wk[o][c] = Wk[o * 6 + c];
    }

    float acc = 0.0f;
    for (int q = blockIdx.x * NTHR + threadIdx.x; q < NQUAD; q += NBLK * NTHR) {
        // batch-interleaved mapping: b uniform per block, batches spread
        // across consecutive blocks for vc load balance over CUs/XCDs
        int blk = q >> 8;                               // block index
        int b   = blk & (BB - 1);                       // batch (block-uniform)
        int hw  = ((((blk >> 4) << 8) | (q & 255)) << 2);  // 4-pixel base in plane
        float sq = s_sq[b], sq1 = s_sq1[b], md = s_mod[b];
        // vc block-uniform -> SGPR: scalar branches, masked views' loads never issued
        const int vcs = __builtin_amdgcn_readfirstlane(s_vc[b]);

        float4 y0v[3], nzv[3];
        #pragma unroll
        for (int c = 0; c < 3; ++c) {
            y0v[c] = *(const float4*)(y0    + (b * 3 + c) * HW_ + hw);
            nzv[c] = *(const float4*)(noise + (b * 3 + c) * HW_ + hw);
        }
        // conditional ycond loads: only views v < vc are ever needed
        float4 ycv[VV][3];
        #pragma unroll
        for (int v = 0; v < VV; ++v) {
            if (v < vcs) {
                #pragma unroll
                for (int c = 0; c < 3; ++c) {
                    ycv[v][c] = *(const float4*)(ycond + ((b * VV + v) * 3 + c) * HW_ + hw);
                }
            } else {
                #pragma unroll
                for (int c = 0; c < 3; ++c) {
                    ycv[v][c] = make_float4(0.f, 0.f, 0.f, 0.f);
                }
            }
        }

        #pragma unroll
        for (int j = 0; j < 4; ++j) {
            // y_noisy for this pixel
            float yn0 = fmaf(sq, F4(y0v[0], j), sq1 * F4(nzv[0], j));
            float yn1 = fmaf(sq, F4(y0v[1], j), sq1 * F4(nzv[1], j));
            float yn2 = fmaf(sq, F4(y0v[2], j), sq1 * F4(nzv[2], j));

            // v-independent part of the 4x6 linear layer
            float base[4];
            #pragma unroll
            for (int o = 0; o < 4; ++o) {
                base[o] = fmaf(wk[o][3], yn0,
                          fmaf(wk[o][4], yn1,
                          fmaf(wk[o][5], yn2, bkr[o] + md)));
            }

            // single-pass masked softmax over views, LINEARIZED:
            //   noise_hat_o * S = A_o . (sum_v w_v x_v) + base_o * S
            // masked views skipped entirely under scalar branch.
            // (no max-shift: |logit| <= ~1.5, absmax 0.0 validated r2-r12)
            float S = 0.0f, sx0 = 0.0f, sx1 = 0.0f, sx2 = 0.0f;
            #pragma unroll
            for (int v = 0; v < VV; ++v) {
                if (v < vcs) {
                    float x0 = F4(ycv[v][0], j);
                    float x1 = F4(ycv[v][1], j);
                    float x2 = F4(ycv[v][2], j);
                    float o3 = fmaf(wk[3][0], x0,
                               fmaf(wk[3][1], x1,
                               fmaf(wk[3][2], x2, base[3])));
                    float w  = __expf(o3);
                    S   += w;
                    sx0  = fmaf(w, x0, sx0);
                    sx1  = fmaf(w, x1, sx1);
                    sx2  = fmaf(w, x2, sx2);
                }
            }
            float nh0 = fmaf(wk[0][0], sx0,
                        fmaf(wk[0][1], sx1,
                        fmaf(wk[0][2], sx2, base[0] * S)));
            float nh1 = fmaf(wk[1][0], sx0,
                        fmaf(wk[1][1], sx1,
                        fmaf(wk[1][2], sx2, base[1] * S)));
            float nh2 = fmaf(wk[2][0], sx0,
                        fmaf(wk[2][1], sx1,
                        fmaf(wk[2][2], sx2, base[2] * S)));
            float invS = 1.0f / S;
            float d0 = F4(nzv[0], j) - nh0 * invS;
            float d1 = F4(nzv[1], j) - nh1 * invS;
            float d2 = F4(nzv[2], j) - nh2 * invS;
            acc = fmaf(d0, d0, fmaf(d1, d1, fmaf(d2, d2, acc)));
        }
    }

    // deterministic block reduction
    s_red[threadIdx.x] = acc;
    __syncthreads();
    #pragma unroll
    for (int s = NTHR / 2; s > 0; s >>= 1) {
        if (threadIdx.x < s) s_red[threadIdx.x] += s_red[threadIdx.x + s];
        __syncthreads();
    }
    if (threadIdx.x == 0) partials[blockIdx.x] = s_red[0];
}

// single-wave reduce: no LDS, no barriers. lane L sums partials[L + 64k]
// (coalesced, fixed order, f64), then fixed-order shfl_down double tree.
__global__ __launch_bounds__(64) void pvs_reduce(const float* __restrict__ partials,
                                                 float* __restrict__ out)
{
    const int lane = threadIdx.x;
    double a = 0.0;
    #pragma unroll
    for (int k = 0; k < NBLK / 64; ++k) {
        a += (double)partials[lane + (k << 6)];
    }
    #pragma unroll
    for (int s = 32; s > 0; s >>= 1) {
        a += __shfl_down(a, s, 64);
    }
    if (lane == 0) out[0] = (float)(a / NPIX_D);
}

extern "C" void kernel_launch(void* const* d_in, const int* in_sizes, int n_in,
                              void* d_out, int out_size, void* d_ws, size_t ws_size,
                              hipStream_t stream) {
    const float* y0      = (const float*)d_in[0];
    const float* ycond   = (const float*)d_in[1];
    const float* angle   = (const float*)d_in[2];
    const float* noise   = (const float*)d_in[3];
    const float* rand_u  = (const float*)d_in[4];
    const float* Wk      = (const float*)d_in[5];
    const float* bk      = (const float*)d_in[6];
    const float* gammas  = (const float*)d_in[7];
    const int*   vcp     = (const int*)d_in[8];
    const int*   tt      = (const int*)d_in[9];

    float* partials = (float*)d_ws;
    float* out      = (float*)d_out;

    pvs_main<<<NBLK, NTHR, 0, stream>>>(y0, ycond, angle, noise, rand_u,
                                        Wk, bk, gammas, vcp, tt, partials);
    pvs_reduce<<<1, 64, 0, stream>>>(partials, out);
}

// Round 14
// 23.166 us; speedup vs baseline: 1.1447x; 1.0097x over previous
//
#include <hip/hip_runtime.h>
#include <math.h>

#define BB   16
#define VV   8
#define HW_  65536            // 256*256
#define HWQ  16384            // HW_/4
#define NQUAD (BB * HWQ)      // 262144 quads (4 pixels each)
#define NBLK 1024
#define NTHR 256
#define NPIX_D 3145728.0      // B*3*H*W (mean denominator)

// access j-th float of a float4 (static j under full unroll)
#define F4(a, j) (((const float*)&(a))[j])

// min 3 waves/EU: caps VGPR at 168 — fits the ~160 peak (30 float4 load
// results = 120 + temps/accums ~40; wk/bk are SGPR via s_load) WITHOUT
// forcing the load-sinking failure mode (r2/r3).
__global__ __launch_bounds__(NTHR, 3) void pvs_main(
    const float* __restrict__ y0,
    const float* __restrict__ ycond,
    const float* __restrict__ angle,
    const float* __restrict__ noise,
    const float* __restrict__ rand_u,
    const float* __restrict__ Wk,
    const float* __restrict__ bk,
    const float* __restrict__ gammas,
    const int*   __restrict__ view_count,
    const int*   __restrict__ tt,
    float* __restrict__ partials)
{
    __shared__ float s_sq[BB], s_sq1[BB], s_mod[BB];
    __shared__ int   s_vc[BB];
    __shared__ float s_red[NTHR];

    if (threadIdx.x < BB) {
        int b = threadIdx.x;
        int t = tt[b];
        float g1 = gammas[t - 1];
        float g2 = gammas[t];
        float sg = (g2 - g1) * rand_u[b] + g1;
        s_sq[b]  = sqrtf(sg);
        s_sq1[b] = sqrtf(1.0f - sg);
        s_mod[b] = 0.1f * (sg + angle[b]);
        s_vc[b]  = view_count[b];
    }
    __syncthreads();

    // Wk (4,6) row-major, bk (4) — uniform, SGPR-resident via s_load
    float wk[4][6], bkr[4];
    #pragma unroll
    for (int o = 0; o < 4; ++o) {
        bkr[o] = bk[o];
        #pragma unroll
        for (int c = 0; c < 6; ++c) wk[o][c] = Wk[o * 6 + c];
    }

    float acc = 0.0f;
    for (int q = blockIdx.x * NTHR + threadIdx.x; q < NQUAD; q += NBLK * NTHR) {
        // batch-interleaved mapping: b uniform per block, batches spread
        // across consecutive blocks for vc load balance over CUs/XCDs
        int blk = q >> 8;                               // block index
        int b   = blk & (BB - 1);                       // batch (block-uniform)
        int hw  = ((((blk >> 4) << 8) | (q & 255)) << 2);  // 4-pixel base in plane
        float sq = s_sq[b], sq1 = s_sq1[b], md = s_mod[b];
        // vc block-uniform -> SGPR: scalar branches, masked views' loads never issued
        const int vcs = __builtin_amdgcn_readfirstlane(s_vc[b]);

        float4 y0v[3], nzv[3];
        #pragma unroll
        for (int c = 0; c < 3; ++c) {
            y0v[c] = *(const float4*)(y0    + (b * 3 + c) * HW_ + hw);
            nzv[c] = *(const float4*)(noise + (b * 3 + c) * HW_ + hw);
        }
        // conditional ycond loads: only views v < vc are ever needed
        float4 ycv[VV][3];
        #pragma unroll
        for (int v = 0; v < VV; ++v) {
            if (v < vcs) {
                #pragma unroll
                for (int c = 0; c < 3; ++c) {
                    ycv[v][c] = *(const float4*)(ycond + ((b * VV + v) * 3 + c) * HW_ + hw);
                }
            } else {
                #pragma unroll
                for (int c = 0; c < 3; ++c) {
                    ycv[v][c] = make_float4(0.f, 0.f, 0.f, 0.f);
                }
            }
        }

        #pragma unroll
        for (int j = 0; j < 4; ++j) {
            // y_noisy for this pixel
            float yn0 = fmaf(sq, F4(y0v[0], j), sq1 * F4(nzv[0], j));
            float yn1 = fmaf(sq, F4(y0v[1], j), sq1 * F4(nzv[1], j));
            float yn2 = fmaf(sq, F4(y0v[2], j), sq1 * F4(nzv[2], j));

            // v-independent part of the 4x6 linear layer
            float base[4];
            #pragma unroll
            for (int o = 0; o < 4; ++o) {
                base[o] = fmaf(wk[o][3], yn0,
                          fmaf(wk[o][4], yn1,
                          fmaf(wk[o][5], yn2, bkr[o] + md)));
            }

            // single-pass masked softmax over views, LINEARIZED:
            //   noise_hat_o * S = A_o . (sum_v w_v x_v) + base_o * S
            // masked views skipped entirely under scalar branch.
            // (no max-shift: |logit| <= ~1.5, absmax 0.0 validated r2-r13)
            float S = 0.0f, sx0 = 0.0f, sx1 = 0.0f, sx2 = 0.0f;
            #pragma unroll
            for (int v = 0; v < VV; ++v) {
                if (v < vcs) {
                    float x0 = F4(ycv[v][0], j);
                    float x1 = F4(ycv[v][1], j);
                    float x2 = F4(ycv[v][2], j);
                    float o3 = fmaf(wk[3][0], x0,
                               fmaf(wk[3][1], x1,
                               fmaf(wk[3][2], x2, base[3])));
                    float w  = __expf(o3);
                    S   += w;
                    sx0  = fmaf(w, x0, sx0);
                    sx1  = fmaf(w, x1, sx1);
                    sx2  = fmaf(w, x2, sx2);
                }
            }
            float nh0 = fmaf(wk[0][0], sx0,
                        fmaf(wk[0][1], sx1,
                        fmaf(wk[0][2], sx2, base[0] * S)));
            float nh1 = fmaf(wk[1][0], sx0,
                        fmaf(wk[1][1], sx1,
                        fmaf(wk[1][2], sx2, base[1] * S)));
            float nh2 = fmaf(wk[2][0], sx0,
                        fmaf(wk[2][1], sx1,
                        fmaf(wk[2][2], sx2, base[2] * S)));
            float invS = 1.0f / S;
            float d0 = F4(nzv[0], j) - nh0 * invS;
            float d1 = F4(nzv[1], j) - nh1 * invS;
            float d2 = F4(nzv[2], j) - nh2 * invS;
            acc = fmaf(d0, d0, fmaf(d1, d1, fmaf(d2, d2, acc)));
        }
    }

    // deterministic block reduction
    s_red[threadIdx.x] = acc;
    __syncthreads();
    #pragma unroll
    for (int s = NTHR / 2; s > 0; s >>= 1) {
        if (threadIdx.x < s) s_red[threadIdx.x] += s_red[threadIdx.x + s];
        __syncthreads();
    }
    if (threadIdx.x == 0) partials[blockIdx.x] = s_red[0];
}

// single-wave reduce: no LDS, no barriers. lane L sums partials[L + 64k]
// (coalesced, fixed order, f64), then fixed-order shfl_down double tree.
__global__ __launch_bounds__(64) void pvs_reduce(const float* __restrict__ partials,
                                                 float* __restrict__ out)
{
    const int lane = threadIdx.x;
    double a = 0.0;
    #pragma unroll
    for (int k = 0; k < NBLK / 64; ++k) {
        a += (double)partials[lane + (k << 6)];
    }
    #pragma unroll
    for (int s = 32; s > 0; s >>= 1) {
        a += __shfl_down(a, s, 64);
    }
    if (lane == 0) out[0] = (float)(a / NPIX_D);
}

extern "C" void kernel_launch(void* const* d_in, const int* in_sizes, int n_in,
                              void* d_out, int out_size, void* d_ws, size_t ws_size,
                              hipStream_t stream) {
    const float* y0      = (const float*)d_in[0];
    const float* ycond   = (const float*)d_in[1];
    const float* angle   = (const float*)d_in[2];
    const float* noise   = (const float*)d_in[3];
    const float* rand_u  = (const float*)d_in[4];
    const float* Wk      = (const float*)d_in[5];
    const float* bk      = (const float*)d_in[6];
    const float* gammas  = (const float*)d_in[7];
    const int*   vcp     = (const int*)d_in[8];
    const int*   tt      = (const int*)d_in[9];

    float* partials = (float*)d_ws;
    float* out      = (float*)d_out;

    pvs_main<<<NBLK, NTHR, 0, stream>>>(y0, ycond, angle, noise, rand_u,
                                        Wk, bk, gammas, vcp, tt, partials);
    pvs_reduce<<<1, 64, 0, stream>>>(partials, out);
}